// Round 18
// baseline (2881.735 us; speedup 1.0000x reference)
//
#include <hip/hip_runtime.h>
#include <hip/hip_bf16.h>
#include <float.h>

#define NB 64
#define HD 1024
#define H3 3072
#define NC6 6144
#define NV 32000
#define TSTEPS 32
#define LBLK 500        // logits blocks (64 cols each)
#define BML 512         // bmlow/bmhigh stride (>= LBLK)
#define NKT 16          // 16 K-steps of 64 per GEMM kernel
#define MARGIN_COEF 0.010f
#define MARGIN_ABS  1e-3f
#define MAXCAND 1024

using bf16x8 = __attribute__((ext_vector_type(8))) short;
using f32x4  = __attribute__((ext_vector_type(4))) float;
using s16x4  = __attribute__((ext_vector_type(4))) short;

// pre-swizzle: XOR 16-B blocks within each 128-B segment by (row&7)<<4.
#define SWZ(row, bo) ((((bo) & ~127)) | (((bo) & 112) ^ (((row) & 7) << 4)) | ((bo) & 15))

__device__ __forceinline__ void gl_lds16(const void* g, void* l) {
    __builtin_amdgcn_global_load_lds(
        (const __attribute__((address_space(1))) void*)g,
        (__attribute__((address_space(3))) void*)l, 16, 0, 0);
}
__device__ __forceinline__ float sigmoidf_(float x) {
    return 1.0f / (1.0f + expf(-x));
}
__device__ __forceinline__ float dot4(float4 h, float4 w, float a) {
    return fmaf(h.w, w.w, fmaf(h.z, w.z, fmaf(h.y, w.y, fmaf(h.x, w.x, a))));
}
__device__ __forceinline__ short bf16bits(float x) {
    __hip_bfloat16 b = __float2bfloat16(x);
    return __builtin_bit_cast(short, b);
}
__device__ __forceinline__ float bf16val(short s) {
    __hip_bfloat16 b = __builtin_bit_cast(__hip_bfloat16, s);
    return __bfloat162float(b);
}

// ============ one-time: Wih/Whh -> 2-way split [row][2048] = [w1|w2], pre-swizzled ============
__global__ __launch_bounds__(256) void wsplit2_kernel(
    const float* __restrict__ Wih, const float* __restrict__ Whh,
    short* __restrict__ WihSp, short* __restrict__ WhhSp)
{
    int r = blockIdx.x;             // 0..6143
    const float* src = (r < H3) ? &Wih[(size_t)r * HD] : &Whh[(size_t)(r - H3) * HD];
    char* dst = (char*)((r < H3) ? &WihSp[(size_t)r * 2048] : &WhhSp[(size_t)(r - H3) * 2048]);
    int k = threadIdx.x * 4;
    float4 v = *(const float4*)&src[k];
    float xs[4] = {v.x, v.y, v.z, v.w};
    s16x4 p1, p2;
    #pragma unroll
    for (int e = 0; e < 4; ++e) {
        short s1 = bf16bits(xs[e]);
        short s2 = bf16bits(xs[e] - bf16val(s1));
        p1[e] = s1; p2[e] = s2;
    }
    int bo = k * 2;                 // byte offset of the 8-B unit
    *(s16x4*)(dst + SWZ(r, bo))        = p1;
    *(s16x4*)(dst + SWZ(r, 2048 + bo)) = p2;
}

// ============ one-time: Wout -> Wbf (bf16, pre-swizzled) + wnorm ============
__global__ __launch_bounds__(256) void wbf_kernel(const float* __restrict__ W,
                                                  short* __restrict__ Wbf,
                                                  float* __restrict__ wnorm)
{
    int r = blockIdx.x, tdx = threadIdx.x;
    float4 v = *(const float4*)&W[(size_t)r * HD + tdx * 4];
    s16x4 p;
    p[0] = bf16bits(v.x); p[1] = bf16bits(v.y);
    p[2] = bf16bits(v.z); p[3] = bf16bits(v.w);
    char* dst = (char*)(Wbf + (size_t)r * HD);
    *(s16x4*)(dst + SWZ(r, tdx * 8)) = p;
    float ss = v.x*v.x + v.y*v.y + v.z*v.z + v.w*v.w;
    #pragma unroll
    for (int off = 32; off; off >>= 1) ss += __shfl_xor(ss, off);
    __shared__ float red[4];
    if ((tdx & 63) == 0) red[tdx >> 6] = ss;
    __syncthreads();
    if (tdx == 0) wnorm[r] = sqrtf(red[0] + red[1] + red[2] + red[3]);
}

// ============ init: ht4 + Hsp + Xsp (pre-swizzled) + hnorm ============
__global__ __launch_bounds__(256) void init_kernel(
    const float* __restrict__ zs, const float* __restrict__ cs,
    const float* __restrict__ emb,
    float4* __restrict__ ht4, short* __restrict__ Hsp, short* __restrict__ Xsp,
    float* __restrict__ hnorm)
{
    int b = blockIdx.x;
    int kg = threadIdx.x;
    int j = kg * 4;
    float4 v;
    if (j < 512) v = *(const float4*)&zs[b * 512 + j];
    else         v = *(const float4*)&cs[b * 512 + (j - 512)];
    ht4[kg * NB + b] = v;
    float hs[4] = {v.x, v.y, v.z, v.w};
    s16x4 p1, p2;
    #pragma unroll
    for (int e = 0; e < 4; ++e) {
        short s1 = bf16bits(hs[e]);
        short s2 = bf16bits(hs[e] - bf16val(s1));
        p1[e] = s1; p2[e] = s2;
    }
    int bo = j * 2;
    char* hdst = (char*)(Hsp + (size_t)b * 2048);
    *(s16x4*)(hdst + SWZ(b, bo))        = p1;
    *(s16x4*)(hdst + SWZ(b, 2048 + bo)) = p2;

    float4 x = *(const float4*)&emb[HD + j];  // SOS = 1
    float xs[4] = {x.x, x.y, x.z, x.w};
    #pragma unroll
    for (int e = 0; e < 4; ++e) {
        short s1 = bf16bits(xs[e]);
        short s2 = bf16bits(xs[e] - bf16val(s1));
        p1[e] = s1; p2[e] = s2;
    }
    char* xdst = (char*)(Xsp + (size_t)b * 2048);
    *(s16x4*)(xdst + SWZ(b, bo))        = p1;
    *(s16x4*)(xdst + SWZ(b, 2048 + bo)) = p2;

    float ss = hs[0]*hs[0] + hs[1]*hs[1] + hs[2]*hs[2] + hs[3]*hs[3];
    #pragma unroll
    for (int off = 32; off; off >>= 1) ss += __shfl_xor(ss, off);
    __shared__ float red[4];
    if ((kg & 63) == 0) red[kg >> 6] = ss;
    __syncthreads();
    if (kg == 0) hnorm[b] = sqrtf(red[0] + red[1] + red[2] + red[3]);
}

// ============ gates: 2-way-split full-product MFMA, K-split 4, gload_lds staging ============
__global__ __launch_bounds__(256, 2) void gates_mfma(
    const short* __restrict__ Xsp, const short* __restrict__ Hsp,
    const short* __restrict__ WihSp, const short* __restrict__ WhhSp,
    float* __restrict__ gpart)
{
    __shared__ __align__(16) char tile[2][16384];

    const int tid = threadIdx.x;
    const int wv = tid >> 6, l = tid & 63;
    int cg = blockIdx.x >> 2;
    int ks = blockIdx.x & 3;
    int c0 = cg * 64;
    bool isH = c0 >= H3;
    const short* __restrict__ Asrc = isH ? Hsp : Xsp;
    const short* __restrict__ Wsrc = isH ? WhhSp : WihSp;
    int wc0 = c0 - (isH ? H3 : 0);
    int k0 = ks * 1024;
    int ka0 = (k0 & 1023) + (((k0 >> 10) & 1) << 10);   // A region: a1,a2,a1,a2
    int kw0 = (k0 & 1023) + ((k0 >> 11) << 10);         // W region: w1,w1,w2,w2

    const short* srows[4];
    int lof[4];
    #pragma unroll
    for (int i = 0; i < 4; ++i) {
        int slot = i * 256 + tid;
        int row = slot >> 3;
        int kb  = (slot & 7) * 16;
        const short* g = (row < 64)
            ? (Asrc + (size_t)row * 2048 + ka0)
            : (Wsrc + (size_t)(wc0 + row - 64) * 2048 + kw0);
        srows[i] = g + (kb >> 1);
        lof[i] = slot * 16;
    }

    int a_off[4][2], b_off[2];
    #pragma unroll
    for (int m = 0; m < 4; ++m)
        #pragma unroll
        for (int kf = 0; kf < 2; ++kf) {
            int row = m * 16 + (l & 15);
            int kb = kf * 64 + (l >> 4) * 16;
            a_off[m][kf] = row * 128 + (kb ^ ((row & 7) << 4));
        }
    #pragma unroll
    for (int kf = 0; kf < 2; ++kf) {
        int row = 64 + wv * 16 + (l & 15);
        int kb = kf * 64 + (l >> 4) * 16;
        b_off[kf] = row * 128 + (kb ^ ((row & 7) << 4));
    }

    f32x4 acc[4] = {};

    #pragma unroll
    for (int i = 0; i < 4; ++i) gl_lds16(srows[i], tile[0] + lof[i]);
    __syncthreads();

    int cur = 0;
    #pragma unroll 1
    for (int kt = 0; kt < NKT; ++kt) {
        if (kt + 1 < NKT) {
            #pragma unroll
            for (int i = 0; i < 4; ++i)
                gl_lds16(srows[i] + (size_t)(kt + 1) * 64, tile[cur ^ 1] + lof[i]);
        }
        char* buf = tile[cur];
        #pragma unroll
        for (int kf = 0; kf < 2; ++kf) {
            bf16x8 bfrag = *(const bf16x8*)(buf + b_off[kf]);
            #pragma unroll
            for (int m = 0; m < 4; ++m) {
                bf16x8 afrag = *(const bf16x8*)(buf + a_off[m][kf]);
                acc[m] = __builtin_amdgcn_mfma_f32_16x16x32_bf16(afrag, bfrag, acc[m], 0, 0, 0);
            }
        }
        __syncthreads();
        cur ^= 1;
    }

    int colw = c0 + wv * 16 + (l & 15);
    #pragma unroll
    for (int m = 0; m < 4; ++m)
        #pragma unroll
        for (int j = 0; j < 4; ++j) {
            int row = m * 16 + (l >> 4) * 4 + j;
            gpart[(size_t)(ks * NB + row) * NC6 + colw] = acc[m][j];
        }
}

// ============ GRU fuse + hsplit epilogue (pre-swizzled Hsp) + hnorm ============
__global__ __launch_bounds__(256) void gru_fuse(
    const float* __restrict__ gpart,
    const float* __restrict__ bih, const float* __restrict__ bhh,
    float4* __restrict__ ht4, short* __restrict__ Hsp,
    float* __restrict__ hnorm)
{
    int b = blockIdx.x;
    int kg = threadIdx.x;
    int j0 = kg * 4;
    float4 ir = {}, iz = {}, in_ = {}, hr = {}, hz = {}, hn = {};
    #pragma unroll
    for (int ks = 0; ks < 4; ++ks) {
        const float* g = gpart + (size_t)(ks * NB + b) * NC6;
        float4 a;
        a = *(const float4*)&g[j0];             ir.x+=a.x; ir.y+=a.y; ir.z+=a.z; ir.w+=a.w;
        a = *(const float4*)&g[HD + j0];        iz.x+=a.x; iz.y+=a.y; iz.z+=a.z; iz.w+=a.w;
        a = *(const float4*)&g[2*HD + j0];      in_.x+=a.x; in_.y+=a.y; in_.z+=a.z; in_.w+=a.w;
        a = *(const float4*)&g[H3 + j0];        hr.x+=a.x; hr.y+=a.y; hr.z+=a.z; hr.w+=a.w;
        a = *(const float4*)&g[H3 + HD + j0];   hz.x+=a.x; hz.y+=a.y; hz.z+=a.z; hz.w+=a.w;
        a = *(const float4*)&g[H3 + 2*HD + j0]; hn.x+=a.x; hn.y+=a.y; hn.z+=a.z; hn.w+=a.w;
    }
    float4 vbi0 = *(const float4*)&bih[j0];
    float4 vbi1 = *(const float4*)&bih[HD + j0];
    float4 vbi2 = *(const float4*)&bih[2*HD + j0];
    float4 vbh0 = *(const float4*)&bhh[j0];
    float4 vbh1 = *(const float4*)&bhh[HD + j0];
    float4 vbh2 = *(const float4*)&bhh[2*HD + j0];
    float4 hv = ht4[kg * NB + b];
    float irv[4] = {ir.x+vbi0.x, ir.y+vbi0.y, ir.z+vbi0.z, ir.w+vbi0.w};
    float izv[4] = {iz.x+vbi1.x, iz.y+vbi1.y, iz.z+vbi1.z, iz.w+vbi1.w};
    float inv[4] = {in_.x+vbi2.x, in_.y+vbi2.y, in_.z+vbi2.z, in_.w+vbi2.w};
    float hrv[4] = {hr.x+vbh0.x, hr.y+vbh0.y, hr.z+vbh0.z, hr.w+vbh0.w};
    float hzv[4] = {hz.x+vbh1.x, hz.y+vbh1.y, hz.z+vbh1.z, hz.w+vbh1.w};
    float hnv[4] = {hn.x+vbh2.x, hn.y+vbh2.y, hn.z+vbh2.z, hn.w+vbh2.w};
    float hvv[4] = {hv.x, hv.y, hv.z, hv.w};
    float o[4];
    #pragma unroll
    for (int u = 0; u < 4; ++u) {
        float r = sigmoidf_(irv[u] + hrv[u]);
        float z = sigmoidf_(izv[u] + hzv[u]);
        float n = tanhf(inv[u] + r * hnv[u]);
        o[u] = (1.0f - z) * n + z * hvv[u];
    }
    ht4[kg * NB + b] = make_float4(o[0], o[1], o[2], o[3]);

    s16x4 p1, p2;
    #pragma unroll
    for (int e = 0; e < 4; ++e) {
        short s1 = bf16bits(o[e]);
        short s2 = bf16bits(o[e] - bf16val(s1));
        p1[e] = s1; p2[e] = s2;
    }
    int bo = j0 * 2;
    char* hdst = (char*)(Hsp + (size_t)b * 2048);
    *(s16x4*)(hdst + SWZ(b, bo))        = p1;
    *(s16x4*)(hdst + SWZ(b, 2048 + bo)) = p2;

    float ss = o[0]*o[0] + o[1]*o[1] + o[2]*o[2] + o[3]*o[3];
    #pragma unroll
    for (int off = 32; off; off >>= 1) ss += __shfl_xor(ss, off);
    __shared__ float red[4];
    if ((kg & 63) == 0) red[kg >> 6] = ss;
    __syncthreads();
    if (kg == 0) hnorm[b] = sqrtf(red[0] + red[1] + red[2] + red[3]);
}

// ============ logits screen: bf16 MFMA (gload_lds) -> lb + per-block low/high bound maxes ============
__global__ __launch_bounds__(256, 2) void logits_lb(
    const short* __restrict__ Hsp, const short* __restrict__ Wbf,
    const float* __restrict__ bout, const float* __restrict__ wnorm,
    const float* __restrict__ hnorm,
    float* __restrict__ lb, float* __restrict__ bmlow, float* __restrict__ bmhigh)
{
    __shared__ __align__(16) char tile[2][16384];
    __shared__ float smax[64][4];
    __shared__ float shigh[64][4];

    const int tid = threadIdx.x;
    const int wv = tid >> 6, l = tid & 63;
    const int blk = blockIdx.x;

    const short* srows[4];
    int lof[4];
    #pragma unroll
    for (int i = 0; i < 4; ++i) {
        int slot = i * 256 + tid;
        int row = slot >> 3;
        int kb  = (slot & 7) * 16;
        const short* g = (row < 64)
            ? (Hsp + (size_t)row * 2048)                      // h1 half (first 1024)
            : (Wbf + ((size_t)(blk * 64 + (row - 64))) * HD);
        srows[i] = g + (kb >> 1);
        lof[i] = slot * 16;
    }

    int a_off[4][2], b_off[2];
    #pragma unroll
    for (int m = 0; m < 4; ++m)
        #pragma unroll
        for (int kf = 0; kf < 2; ++kf) {
            int row = m * 16 + (l & 15);
            int kb = kf * 64 + (l >> 4) * 16;
            a_off[m][kf] = row * 128 + (kb ^ ((row & 7) << 4));
        }
    #pragma unroll
    for (int kf = 0; kf < 2; ++kf) {
        int row = 64 + wv * 16 + (l & 15);
        int kb = kf * 64 + (l >> 4) * 16;
        b_off[kf] = row * 128 + (kb ^ ((row & 7) << 4));
    }

    f32x4 acc[4] = {};

    #pragma unroll
    for (int i = 0; i < 4; ++i) gl_lds16(srows[i], tile[0] + lof[i]);
    __syncthreads();

    int cur = 0;
    #pragma unroll 1
    for (int kt = 0; kt < NKT; ++kt) {
        if (kt + 1 < NKT) {
            #pragma unroll
            for (int i = 0; i < 4; ++i)
                gl_lds16(srows[i] + (size_t)(kt + 1) * 64, tile[cur ^ 1] + lof[i]);
        }
        char* buf = tile[cur];
        #pragma unroll
        for (int kf = 0; kf < 2; ++kf) {
            bf16x8 bfrag = *(const bf16x8*)(buf + b_off[kf]);
            #pragma unroll
            for (int m = 0; m < 4; ++m) {
                bf16x8 afrag = *(const bf16x8*)(buf + a_off[m][kf]);
                acc[m] = __builtin_amdgcn_mfma_f32_16x16x32_bf16(afrag, bfrag, acc[m], 0, 0, 0);
            }
        }
        __syncthreads();
        cur ^= 1;
    }

    int col = blk * 64 + wv * 16 + (l & 15);
    float bo = bout[col];
    float wn = wnorm[col];
    float selmax = -FLT_MAX, selhigh = -FLT_MAX;
    int pick = l & 15;
    #pragma unroll
    for (int m = 0; m < 4; ++m) {
        #pragma unroll
        for (int j = 0; j < 4; ++j) {
            int row = m * 16 + (l >> 4) * 4 + j;
            float lbv = acc[m][j] + bo;
            lb[(size_t)row * NV + col] = lbv;
            float marg = MARGIN_COEF * hnorm[row] * wn + MARGIN_ABS;
            float low = lbv - marg;
            float high = lbv + marg;
            #pragma unroll
            for (int mask = 1; mask <= 8; mask <<= 1) {
                low  = fmaxf(low,  __shfl_xor(low,  mask, 64));
                high = fmaxf(high, __shfl_xor(high, mask, 64));
            }
            if (pick == m * 4 + j) { selmax = low; selhigh = high; }
        }
    }
    int row = ((l & 15) >> 2) * 16 + (l >> 4) * 4 + (l & 3);
    smax[row][wv] = selmax;
    shigh[row][wv] = selhigh;
    __syncthreads();
    if (wv == 0) {
        float v = fmaxf(fmaxf(smax[l][0], smax[l][1]), fmaxf(smax[l][2], smax[l][3]));
        float h = fmaxf(fmaxf(shigh[l][0], shigh[l][1]), fmaxf(shigh[l][2], shigh[l][3]));
        bmlow[(size_t)l * BML + blk] = v;
        bmhigh[(size_t)l * BML + blk] = h;
    }
}

// ============ select+gather: per-batch block. T reduce, qualifying-block scan, exact rescore,
// winner -> resps + Xsp. No global atomics; fully deterministic. grid 64 x 256 thr. ============
__global__ __launch_bounds__(256) void select_gather(
    const float* __restrict__ lb, const float* __restrict__ wnorm,
    const float* __restrict__ hnorm,
    const float* __restrict__ bmlow, const float* __restrict__ bmhigh,
    const float* __restrict__ Wout, const float* __restrict__ bout,
    const float4* __restrict__ ht4, const float* __restrict__ emb,
    int* __restrict__ resps, int t, short* __restrict__ Xsp)
{
    int b = blockIdx.x;
    int tid = threadIdx.x, wv = tid >> 6;
    float coef = MARGIN_COEF * hnorm[b];

    __shared__ float tred[4];
    __shared__ float rsum[4];
    __shared__ int qcount, scount, stok;
    __shared__ int qblk[BML];
    __shared__ int cand[MAXCAND];
    if (tid == 0) { qcount = 0; scount = 0; }

    // T[b] = max over blocks of bmlow (2 KB, deterministic)
    float tv = -FLT_MAX;
    for (int i = tid; i < LBLK; i += 256) tv = fmaxf(tv, bmlow[(size_t)b * BML + i]);
    #pragma unroll
    for (int off = 32; off; off >>= 1) tv = fmaxf(tv, __shfl_xor(tv, off));
    if ((tid & 63) == 0) tred[wv] = tv;
    __syncthreads();
    float tb = fmaxf(fmaxf(tred[0], tred[1]), fmaxf(tred[2], tred[3]));

    // qualifying blocks: bmhigh >= T (provably the only possible candidate holders)
    for (int i = tid; i < LBLK; i += 256) {
        if (bmhigh[(size_t)b * BML + i] >= tb) {
            int s = atomicAdd(&qcount, 1);   // LDS atomic
            qblk[s] = i;
        }
    }
    __syncthreads();
    int qn = qcount;

    // candidate cols within qualifying blocks
    const float* lbr = lb + (size_t)b * NV;
    for (int q = 0; q < qn; ++q) {
        if (tid < 64) {
            int c = qblk[q] * 64 + tid;
            if (lbr[c] + (coef * wnorm[c] + MARGIN_ABS) >= tb) {
                int s = atomicAdd(&scount, 1);
                if (s < MAXCAND) cand[s] = c;
            }
        }
    }
    __syncthreads();
    int n = scount < MAXCAND ? scount : MAXCAND;

    // exact fp32 rescore; winner = order-invariant max (min index on tie)
    float4 h4 = ht4[tid * NB + b];
    float bv = -FLT_MAX; int bc = 0x7fffffff;
    for (int s = 0; s < n; ++s) {
        int c = cand[s];
        float4 w4 = *(const float4*)&Wout[(size_t)c * HD + tid * 4];
        float p = dot4(h4, w4, 0.0f);
        #pragma unroll
        for (int off = 32; off; off >>= 1) p += __shfl_xor(p, off);
        if ((tid & 63) == 0) rsum[wv] = p;
        __syncthreads();
        if (tid == 0) {
            float tot = rsum[0] + rsum[1] + rsum[2] + rsum[3] + bout[c];
            if (tot > bv || (tot == bv && c < bc)) { bv = tot; bc = c; }
        }
        __syncthreads();
    }
    if (tid == 0) { resps[b * TSTEPS + t] = bc; stok = bc; }
    __syncthreads();

    // gather: split emb row of winner into Xsp (pre-swizzled)
    int tok = stok;
    int k = tid * 4;
    float4 e = *(const float4*)&emb[(size_t)tok * HD + k];
    float xs[4] = {e.x, e.y, e.z, e.w};
    s16x4 p1, p2;
    #pragma unroll
    for (int u = 0; u < 4; ++u) {
        short s1 = bf16bits(xs[u]);
        short s2 = bf16bits(xs[u] - bf16val(s1));
        p1[u] = s1; p2[u] = s2;
    }
    int bo = k * 2;
    char* xdst = (char*)(Xsp + (size_t)b * 2048);
    *(s16x4*)(xdst + SWZ(b, bo))        = p1;
    *(s16x4*)(xdst + SWZ(b, 2048 + bo)) = p2;
}

// ---------------- resp_lens ----------------
__global__ void resp_lens_kernel(const int* __restrict__ resps, int* __restrict__ lens)
{
    int b = threadIdx.x;
    if (b >= NB) return;
    int len = TSTEPS + 1;
    for (int t = TSTEPS - 1; t >= 0; t--)
        if (resps[b * TSTEPS + t] == 2) len = t + 1;
    lens[b] = len;
}

extern "C" void kernel_launch(void* const* d_in, const int* in_sizes, int n_in,
                              void* d_out, int out_size, void* d_ws, size_t ws_size,
                              hipStream_t stream) {
    const float* zs   = (const float*)d_in[0];
    const float* cs   = (const float*)d_in[1];
    const float* emb  = (const float*)d_in[2];
    const float* Wih  = (const float*)d_in[3];
    const float* Whh  = (const float*)d_in[4];
    const float* bih  = (const float*)d_in[5];
    const float* bhh  = (const float*)d_in[6];
    const float* Wout = (const float*)d_in[7];
    const float* bout = (const float*)d_in[8];
    int* out = (int*)d_out;  // [64*32 resps][64 lens], int32

    char* ws = (char*)d_ws;
    float4* ht4  = (float4*)ws; ws += (size_t)256 * NB * 16;          // 256 KB
    float*  gpart = (float*)ws; ws += (size_t)4 * NB * NC6 * 4;       // 6.3 MB
    short*  Hsp  = (short*)ws;  ws += (size_t)NB * 2048 * 2;          // 256 KB
    short*  Xsp  = (short*)ws;  ws += (size_t)NB * 2048 * 2;          // 256 KB
    float*  wnorm = (float*)ws; ws += (size_t)NV * 4;                 // 128 KB
    float*  hnorm = (float*)ws; ws += 256;
    float*  bmlow = (float*)ws; ws += (size_t)NB * BML * 4;           // 128 KB
    float*  bmhigh = (float*)ws; ws += (size_t)NB * BML * 4;          // 128 KB
    float*  lb   = (float*)ws;  ws += (size_t)NB * NV * 4;            // 8.2 MB
    short*  Wbf  = (short*)ws;  ws += (size_t)NV * HD * 2;            // 65.5 MB
    short*  WihSp = (short*)ws; ws += (size_t)H3 * 2048 * 2;          // 12.6 MB
    short*  WhhSp = (short*)ws; ws += (size_t)H3 * 2048 * 2;          // 12.6 MB

    wsplit2_kernel<<<NC6, 256, 0, stream>>>(Wih, Whh, WihSp, WhhSp);
    wbf_kernel<<<NV, 256, 0, stream>>>(Wout, Wbf, wnorm);
    init_kernel<<<NB, 256, 0, stream>>>(zs, cs, emb, ht4, Hsp, Xsp, hnorm);
    for (int t = 0; t < TSTEPS; t++) {
        gates_mfma<<<96 * 4, 256, 0, stream>>>(Xsp, Hsp, WihSp, WhhSp, gpart);
        gru_fuse<<<NB, 256, 0, stream>>>(gpart, bih, bhh, ht4, Hsp, hnorm);
        logits_lb<<<LBLK, 256, 0, stream>>>(Hsp, Wbf, bout, wnorm, hnorm, lb, bmlow, bmhigh);
        select_gather<<<NB, 256, 0, stream>>>(lb, wnorm, hnorm, bmlow, bmhigh,
                                              Wout, bout, ht4, emb, out, t, Xsp);
    }
    resp_lens_kernel<<<1, 64, 0, stream>>>(out, out + NB * TSTEPS);
}

// Round 19
// 1600.838 us; speedup vs baseline: 1.8001x; 1.8001x over previous
//
#include <hip/hip_runtime.h>
#include <hip/hip_bf16.h>
#include <float.h>

#define NB 64
#define HD 1024
#define H3 3072
#define NC6 6144
#define NV 32000
#define TSTEPS 32
#define LBLK 500        // logits blocks (64 cols each)
#define BML 512         // bmlow stride (>= LBLK)
#define NSLICE 8        // select2 col slices
#define NKT 16          // 16 K-steps of 64 per GEMM kernel
#define MARGIN_COEF 0.010f
#define MARGIN_ABS  1e-3f
#define MAXCAND 1024

using bf16x8 = __attribute__((ext_vector_type(8))) short;
using f32x4  = __attribute__((ext_vector_type(4))) float;
using s16x4  = __attribute__((ext_vector_type(4))) short;

// pre-swizzle: XOR 16-B blocks within each 128-B segment by (row&7)<<4.
#define SWZ(row, bo) ((((bo) & ~127)) | (((bo) & 112) ^ (((row) & 7) << 4)) | ((bo) & 15))

__device__ __forceinline__ void gl_lds16(const void* g, void* l) {
    __builtin_amdgcn_global_load_lds(
        (const __attribute__((address_space(1))) void*)g,
        (__attribute__((address_space(3))) void*)l, 16, 0, 0);
}
__device__ __forceinline__ float sigmoidf_(float x) {
    return 1.0f / (1.0f + expf(-x));
}
__device__ __forceinline__ float dot4(float4 h, float4 w, float a) {
    return fmaf(h.w, w.w, fmaf(h.z, w.z, fmaf(h.y, w.y, fmaf(h.x, w.x, a))));
}
__device__ __forceinline__ short bf16bits(float x) {
    __hip_bfloat16 b = __float2bfloat16(x);
    return __builtin_bit_cast(short, b);
}
__device__ __forceinline__ float bf16val(short s) {
    __hip_bfloat16 b = __builtin_bit_cast(__hip_bfloat16, s);
    return __bfloat162float(b);
}
__device__ __forceinline__ unsigned ordbits(float v) {
    unsigned u = __float_as_uint(v);
    return (u & 0x80000000u) ? ~u : (u | 0x80000000u);
}

// ============ one-time: Wih/Whh -> 2-way split [row][2048] = [w1|w2], pre-swizzled ============
__global__ __launch_bounds__(256) void wsplit2_kernel(
    const float* __restrict__ Wih, const float* __restrict__ Whh,
    short* __restrict__ WihSp, short* __restrict__ WhhSp)
{
    int r = blockIdx.x;             // 0..6143
    const float* src = (r < H3) ? &Wih[(size_t)r * HD] : &Whh[(size_t)(r - H3) * HD];
    char* dst = (char*)((r < H3) ? &WihSp[(size_t)r * 2048] : &WhhSp[(size_t)(r - H3) * 2048]);
    int k = threadIdx.x * 4;
    float4 v = *(const float4*)&src[k];
    float xs[4] = {v.x, v.y, v.z, v.w};
    s16x4 p1, p2;
    #pragma unroll
    for (int e = 0; e < 4; ++e) {
        short s1 = bf16bits(xs[e]);
        short s2 = bf16bits(xs[e] - bf16val(s1));
        p1[e] = s1; p2[e] = s2;
    }
    int bo = k * 2;                 // byte offset of the 8-B unit
    *(s16x4*)(dst + SWZ(r, bo))        = p1;
    *(s16x4*)(dst + SWZ(r, 2048 + bo)) = p2;
}

// ============ one-time: Wout -> Wbf (bf16, pre-swizzled) + wnorm ============
__global__ __launch_bounds__(256) void wbf_kernel(const float* __restrict__ W,
                                                  short* __restrict__ Wbf,
                                                  float* __restrict__ wnorm)
{
    int r = blockIdx.x, tdx = threadIdx.x;
    float4 v = *(const float4*)&W[(size_t)r * HD + tdx * 4];
    s16x4 p;
    p[0] = bf16bits(v.x); p[1] = bf16bits(v.y);
    p[2] = bf16bits(v.z); p[3] = bf16bits(v.w);
    char* dst = (char*)(Wbf + (size_t)r * HD);
    *(s16x4*)(dst + SWZ(r, tdx * 8)) = p;
    float ss = v.x*v.x + v.y*v.y + v.z*v.z + v.w*v.w;
    #pragma unroll
    for (int off = 32; off; off >>= 1) ss += __shfl_xor(ss, off);
    __shared__ float red[4];
    if ((tdx & 63) == 0) red[tdx >> 6] = ss;
    __syncthreads();
    if (tdx == 0) wnorm[r] = sqrtf(red[0] + red[1] + red[2] + red[3]);
}

// ============ init: ht4 + Hsp + Xsp (pre-swizzled) + hnorm + best reset ============
__global__ __launch_bounds__(256) void init_kernel(
    const float* __restrict__ zs, const float* __restrict__ cs,
    const float* __restrict__ emb,
    float4* __restrict__ ht4, short* __restrict__ Hsp, short* __restrict__ Xsp,
    float* __restrict__ hnorm, unsigned long long* __restrict__ best)
{
    int b = blockIdx.x;
    int kg = threadIdx.x;
    int j = kg * 4;
    float4 v;
    if (j < 512) v = *(const float4*)&zs[b * 512 + j];
    else         v = *(const float4*)&cs[b * 512 + (j - 512)];
    ht4[kg * NB + b] = v;
    float hs[4] = {v.x, v.y, v.z, v.w};
    s16x4 p1, p2;
    #pragma unroll
    for (int e = 0; e < 4; ++e) {
        short s1 = bf16bits(hs[e]);
        short s2 = bf16bits(hs[e] - bf16val(s1));
        p1[e] = s1; p2[e] = s2;
    }
    int bo = j * 2;
    char* hdst = (char*)(Hsp + (size_t)b * 2048);
    *(s16x4*)(hdst + SWZ(b, bo))        = p1;
    *(s16x4*)(hdst + SWZ(b, 2048 + bo)) = p2;

    float4 x = *(const float4*)&emb[HD + j];  // SOS = 1
    float xs[4] = {x.x, x.y, x.z, x.w};
    #pragma unroll
    for (int e = 0; e < 4; ++e) {
        short s1 = bf16bits(xs[e]);
        short s2 = bf16bits(xs[e] - bf16val(s1));
        p1[e] = s1; p2[e] = s2;
    }
    char* xdst = (char*)(Xsp + (size_t)b * 2048);
    *(s16x4*)(xdst + SWZ(b, bo))        = p1;
    *(s16x4*)(xdst + SWZ(b, 2048 + bo)) = p2;

    float ss = hs[0]*hs[0] + hs[1]*hs[1] + hs[2]*hs[2] + hs[3]*hs[3];
    #pragma unroll
    for (int off = 32; off; off >>= 1) ss += __shfl_xor(ss, off);
    __shared__ float red[4];
    if ((kg & 63) == 0) red[kg >> 6] = ss;
    __syncthreads();
    if (kg == 0) {
        hnorm[b] = sqrtf(red[0] + red[1] + red[2] + red[3]);
        best[b] = 0ull;
    }
}

// ============ gates: 2-way-split full-product MFMA, K-split 4, gload_lds staging ============
// grid 384: cg = blk>>2 (64 cols of 6144), ks = blk&3 (k'' slice of 1024).
// K''=4096 arranged A'=[a1|a2|a1|a2], W'=[w1|w1|w2|w2] -> all 4 cross terms.
__global__ __launch_bounds__(256, 2) void gates_mfma(
    const short* __restrict__ Xsp, const short* __restrict__ Hsp,
    const short* __restrict__ WihSp, const short* __restrict__ WhhSp,
    float* __restrict__ gpart)
{
    __shared__ __align__(16) char tile[2][16384];

    const int tid = threadIdx.x;
    const int wv = tid >> 6, l = tid & 63;
    int cg = blockIdx.x >> 2;
    int ks = blockIdx.x & 3;
    int c0 = cg * 64;
    bool isH = c0 >= H3;
    const short* __restrict__ Asrc = isH ? Hsp : Xsp;
    const short* __restrict__ Wsrc = isH ? WhhSp : WihSp;
    int wc0 = c0 - (isH ? H3 : 0);
    int k0 = ks * 1024;
    int ka0 = (k0 & 1023) + (((k0 >> 10) & 1) << 10);   // A region: a1,a2,a1,a2
    int kw0 = (k0 & 1023) + ((k0 >> 11) << 10);         // W region: w1,w1,w2,w2

    const short* srows[4];
    int lof[4];
    #pragma unroll
    for (int i = 0; i < 4; ++i) {
        int slot = i * 256 + tid;
        int row = slot >> 3;
        int kb  = (slot & 7) * 16;
        const short* g = (row < 64)
            ? (Asrc + (size_t)row * 2048 + ka0)
            : (Wsrc + (size_t)(wc0 + row - 64) * 2048 + kw0);
        srows[i] = g + (kb >> 1);
        lof[i] = slot * 16;
    }

    int a_off[4][2], b_off[2];
    #pragma unroll
    for (int m = 0; m < 4; ++m)
        #pragma unroll
        for (int kf = 0; kf < 2; ++kf) {
            int row = m * 16 + (l & 15);
            int kb = kf * 64 + (l >> 4) * 16;
            a_off[m][kf] = row * 128 + (kb ^ ((row & 7) << 4));
        }
    #pragma unroll
    for (int kf = 0; kf < 2; ++kf) {
        int row = 64 + wv * 16 + (l & 15);
        int kb = kf * 64 + (l >> 4) * 16;
        b_off[kf] = row * 128 + (kb ^ ((row & 7) << 4));
    }

    f32x4 acc[4] = {};

    #pragma unroll
    for (int i = 0; i < 4; ++i) gl_lds16(srows[i], tile[0] + lof[i]);
    __syncthreads();

    int cur = 0;
    #pragma unroll 1
    for (int kt = 0; kt < NKT; ++kt) {
        if (kt + 1 < NKT) {
            #pragma unroll
            for (int i = 0; i < 4; ++i)
                gl_lds16(srows[i] + (size_t)(kt + 1) * 64, tile[cur ^ 1] + lof[i]);
        }
        char* buf = tile[cur];
        #pragma unroll
        for (int kf = 0; kf < 2; ++kf) {
            bf16x8 bfrag = *(const bf16x8*)(buf + b_off[kf]);
            #pragma unroll
            for (int m = 0; m < 4; ++m) {
                bf16x8 afrag = *(const bf16x8*)(buf + a_off[m][kf]);
                acc[m] = __builtin_amdgcn_mfma_f32_16x16x32_bf16(afrag, bfrag, acc[m], 0, 0, 0);
            }
        }
        __syncthreads();
        cur ^= 1;
    }

    int colw = c0 + wv * 16 + (l & 15);
    #pragma unroll
    for (int m = 0; m < 4; ++m)
        #pragma unroll
        for (int j = 0; j < 4; ++j) {
            int row = m * 16 + (l >> 4) * 4 + j;
            gpart[(size_t)(ks * NB + row) * NC6 + colw] = acc[m][j];
        }
}

// ============ GRU fuse + hsplit epilogue (pre-swizzled Hsp) + hnorm + best reset ============
__global__ __launch_bounds__(256) void gru_fuse(
    const float* __restrict__ gpart,
    const float* __restrict__ bih, const float* __restrict__ bhh,
    float4* __restrict__ ht4, short* __restrict__ Hsp,
    float* __restrict__ hnorm, unsigned long long* __restrict__ best)
{
    int b = blockIdx.x;
    int kg = threadIdx.x;
    int j0 = kg * 4;
    float4 ir = {}, iz = {}, in_ = {}, hr = {}, hz = {}, hn = {};
    #pragma unroll
    for (int ks = 0; ks < 4; ++ks) {
        const float* g = gpart + (size_t)(ks * NB + b) * NC6;
        float4 a;
        a = *(const float4*)&g[j0];             ir.x+=a.x; ir.y+=a.y; ir.z+=a.z; ir.w+=a.w;
        a = *(const float4*)&g[HD + j0];        iz.x+=a.x; iz.y+=a.y; iz.z+=a.z; iz.w+=a.w;
        a = *(const float4*)&g[2*HD + j0];      in_.x+=a.x; in_.y+=a.y; in_.z+=a.z; in_.w+=a.w;
        a = *(const float4*)&g[H3 + j0];        hr.x+=a.x; hr.y+=a.y; hr.z+=a.z; hr.w+=a.w;
        a = *(const float4*)&g[H3 + HD + j0];   hz.x+=a.x; hz.y+=a.y; hz.z+=a.z; hz.w+=a.w;
        a = *(const float4*)&g[H3 + 2*HD + j0]; hn.x+=a.x; hn.y+=a.y; hn.z+=a.z; hn.w+=a.w;
    }
    float4 vbi0 = *(const float4*)&bih[j0];
    float4 vbi1 = *(const float4*)&bih[HD + j0];
    float4 vbi2 = *(const float4*)&bih[2*HD + j0];
    float4 vbh0 = *(const float4*)&bhh[j0];
    float4 vbh1 = *(const float4*)&bhh[HD + j0];
    float4 vbh2 = *(const float4*)&bhh[2*HD + j0];
    float4 hv = ht4[kg * NB + b];
    float irv[4] = {ir.x+vbi0.x, ir.y+vbi0.y, ir.z+vbi0.z, ir.w+vbi0.w};
    float izv[4] = {iz.x+vbi1.x, iz.y+vbi1.y, iz.z+vbi1.z, iz.w+vbi1.w};
    float inv[4] = {in_.x+vbi2.x, in_.y+vbi2.y, in_.z+vbi2.z, in_.w+vbi2.w};
    float hrv[4] = {hr.x+vbh0.x, hr.y+vbh0.y, hr.z+vbh0.z, hr.w+vbh0.w};
    float hzv[4] = {hz.x+vbh1.x, hz.y+vbh1.y, hz.z+vbh1.z, hz.w+vbh1.w};
    float hnv[4] = {hn.x+vbh2.x, hn.y+vbh2.y, hn.z+vbh2.z, hn.w+vbh2.w};
    float hvv[4] = {hv.x, hv.y, hv.z, hv.w};
    float o[4];
    #pragma unroll
    for (int u = 0; u < 4; ++u) {
        float r = sigmoidf_(irv[u] + hrv[u]);
        float z = sigmoidf_(izv[u] + hzv[u]);
        float n = tanhf(inv[u] + r * hnv[u]);
        o[u] = (1.0f - z) * n + z * hvv[u];
    }
    ht4[kg * NB + b] = make_float4(o[0], o[1], o[2], o[3]);

    s16x4 p1, p2;
    #pragma unroll
    for (int e = 0; e < 4; ++e) {
        short s1 = bf16bits(o[e]);
        short s2 = bf16bits(o[e] - bf16val(s1));
        p1[e] = s1; p2[e] = s2;
    }
    int bo = j0 * 2;
    char* hdst = (char*)(Hsp + (size_t)b * 2048);
    *(s16x4*)(hdst + SWZ(b, bo))        = p1;
    *(s16x4*)(hdst + SWZ(b, 2048 + bo)) = p2;

    float ss = o[0]*o[0] + o[1]*o[1] + o[2]*o[2] + o[3]*o[3];
    #pragma unroll
    for (int off = 32; off; off >>= 1) ss += __shfl_xor(ss, off);
    __shared__ float red[4];
    if ((kg & 63) == 0) red[kg >> 6] = ss;
    __syncthreads();
    if (kg == 0) {
        hnorm[b] = sqrtf(red[0] + red[1] + red[2] + red[3]);
        best[b] = 0ull;
    }
}

// ============ logits screen: bf16 MFMA (gload_lds) -> lb + per-block lower-bound max ============
__global__ __launch_bounds__(256, 2) void logits_lb(
    const short* __restrict__ Hsp, const short* __restrict__ Wbf,
    const float* __restrict__ bout, const float* __restrict__ wnorm,
    const float* __restrict__ hnorm,
    float* __restrict__ lb, float* __restrict__ bmlow)
{
    __shared__ __align__(16) char tile[2][16384];
    __shared__ float smax[64][4];

    const int tid = threadIdx.x;
    const int wv = tid >> 6, l = tid & 63;
    const int blk = blockIdx.x;

    const short* srows[4];
    int lof[4];
    #pragma unroll
    for (int i = 0; i < 4; ++i) {
        int slot = i * 256 + tid;
        int row = slot >> 3;
        int kb  = (slot & 7) * 16;
        const short* g = (row < 64)
            ? (Hsp + (size_t)row * 2048)                      // h1 half (first 1024)
            : (Wbf + ((size_t)(blk * 64 + (row - 64))) * HD);
        srows[i] = g + (kb >> 1);
        lof[i] = slot * 16;
    }

    int a_off[4][2], b_off[2];
    #pragma unroll
    for (int m = 0; m < 4; ++m)
        #pragma unroll
        for (int kf = 0; kf < 2; ++kf) {
            int row = m * 16 + (l & 15);
            int kb = kf * 64 + (l >> 4) * 16;
            a_off[m][kf] = row * 128 + (kb ^ ((row & 7) << 4));
        }
    #pragma unroll
    for (int kf = 0; kf < 2; ++kf) {
        int row = 64 + wv * 16 + (l & 15);
        int kb = kf * 64 + (l >> 4) * 16;
        b_off[kf] = row * 128 + (kb ^ ((row & 7) << 4));
    }

    f32x4 acc[4] = {};

    #pragma unroll
    for (int i = 0; i < 4; ++i) gl_lds16(srows[i], tile[0] + lof[i]);
    __syncthreads();

    int cur = 0;
    #pragma unroll 1
    for (int kt = 0; kt < NKT; ++kt) {
        if (kt + 1 < NKT) {
            #pragma unroll
            for (int i = 0; i < 4; ++i)
                gl_lds16(srows[i] + (size_t)(kt + 1) * 64, tile[cur ^ 1] + lof[i]);
        }
        char* buf = tile[cur];
        #pragma unroll
        for (int kf = 0; kf < 2; ++kf) {
            bf16x8 bfrag = *(const bf16x8*)(buf + b_off[kf]);
            #pragma unroll
            for (int m = 0; m < 4; ++m) {
                bf16x8 afrag = *(const bf16x8*)(buf + a_off[m][kf]);
                acc[m] = __builtin_amdgcn_mfma_f32_16x16x32_bf16(afrag, bfrag, acc[m], 0, 0, 0);
            }
        }
        __syncthreads();
        cur ^= 1;
    }

    int col = blk * 64 + wv * 16 + (l & 15);
    float bo = bout[col];
    float wn = wnorm[col];
    float selmax = -FLT_MAX;
    int pick = l & 15;
    #pragma unroll
    for (int m = 0; m < 4; ++m) {
        #pragma unroll
        for (int j = 0; j < 4; ++j) {
            int row = m * 16 + (l >> 4) * 4 + j;
            float lbv = acc[m][j] + bo;
            lb[(size_t)row * NV + col] = lbv;
            float low = lbv - (MARGIN_COEF * hnorm[row] * wn + MARGIN_ABS);
            #pragma unroll
            for (int mask = 1; mask <= 8; mask <<= 1)
                low = fmaxf(low, __shfl_xor(low, mask, 64));
            if (pick == m * 4 + j) selmax = low;
        }
    }
    int row = ((l & 15) >> 2) * 16 + (l >> 4) * 4 + (l & 3);
    smax[row][wv] = selmax;
    __syncthreads();
    if (wv == 0) {
        float v = fmaxf(fmaxf(smax[l][0], smax[l][1]), fmaxf(smax[l][2], smax[l][3]));
        bmlow[(size_t)l * BML + blk] = v;
    }
}

// ============ select: inline T reduce + candidates + exact fp32 rescore + commit ============
// grid 64*NSLICE: b = blk>>3, slice = blk&7 (4000 cols each). 256 thr.
__global__ __launch_bounds__(256) void select2_kernel(
    const float* __restrict__ lb, const float* __restrict__ wnorm,
    const float* __restrict__ hnorm, const float* __restrict__ bmlow,
    const float* __restrict__ Wout, const float* __restrict__ bout,
    const float4* __restrict__ ht4,
    unsigned long long* __restrict__ best)
{
    int b = blockIdx.x >> 3, slice = blockIdx.x & 7;
    int tid = threadIdx.x, wv = tid >> 6;
    const float* lbr = lb + (size_t)b * NV;
    float coef = MARGIN_COEF * hnorm[b];

    __shared__ int scount;
    __shared__ int cand[MAXCAND];
    __shared__ float tred[4];
    if (tid == 0) scount = 0;

    // inline T[b]: reduce bmlow row (2 KB, deterministic, no atomics)
    float tv = -FLT_MAX;
    for (int i = tid; i < LBLK; i += 256) tv = fmaxf(tv, bmlow[(size_t)b * BML + i]);
    #pragma unroll
    for (int off = 32; off; off >>= 1) tv = fmaxf(tv, __shfl_xor(tv, off));
    if ((tid & 63) == 0) tred[wv] = tv;
    __syncthreads();
    float tb = fmaxf(fmaxf(tred[0], tred[1]), fmaxf(tred[2], tred[3]));

    int c0 = slice * (NV / NSLICE);
    for (int c = c0 + tid; c < c0 + NV / NSLICE; c += 256) {
        if (lbr[c] + (coef * wnorm[c] + MARGIN_ABS) >= tb) {
            int s = atomicAdd(&scount, 1);
            if (s < MAXCAND) cand[s] = c;
        }
    }
    __syncthreads();
    int n = scount < MAXCAND ? scount : MAXCAND;
    if (n == 0) return;

    float4 h4 = ht4[tid * NB + b];
    __shared__ float rsum[4];
    for (int s = 0; s < n; ++s) {
        int c = cand[s];
        float4 w4 = *(const float4*)&Wout[(size_t)c * HD + tid * 4];
        float p = dot4(h4, w4, 0.0f);
        #pragma unroll
        for (int off = 32; off; off >>= 1) p += __shfl_xor(p, off);
        if ((tid & 63) == 0) rsum[wv] = p;
        __syncthreads();
        if (tid == 0) {
            float tot = rsum[0] + rsum[1] + rsum[2] + rsum[3] + bout[c];
            unsigned long long key =
                ((unsigned long long)ordbits(tot) << 32) | (unsigned)(~c);
            atomicMax(&best[b], key);
        }
        __syncthreads();
    }
}

// ============ gather winner: resps + Xsp (pre-swizzled split emb row) ============
__global__ __launch_bounds__(256) void gather_kernel(
    const unsigned long long* __restrict__ best,
    const float* __restrict__ emb, int* __restrict__ resps, int t,
    short* __restrict__ Xsp)
{
    int b = blockIdx.x, tid = threadIdx.x;
    int c = ~(unsigned)(best[b] & 0xFFFFFFFFull);
    if (tid == 0) resps[b * TSTEPS + t] = c;
    int k = tid * 4;
    float4 e = *(const float4*)&emb[(size_t)c * HD + k];
    float xs[4] = {e.x, e.y, e.z, e.w};
    s16x4 p1, p2;
    #pragma unroll
    for (int u = 0; u < 4; ++u) {
        short s1 = bf16bits(xs[u]);
        short s2 = bf16bits(xs[u] - bf16val(s1));
        p1[u] = s1; p2[u] = s2;
    }
    int bo = k * 2;
    char* xdst = (char*)(Xsp + (size_t)b * 2048);
    *(s16x4*)(xdst + SWZ(b, bo))        = p1;
    *(s16x4*)(xdst + SWZ(b, 2048 + bo)) = p2;
}

// ---------------- resp_lens ----------------
__global__ void resp_lens_kernel(const int* __restrict__ resps, int* __restrict__ lens)
{
    int b = threadIdx.x;
    if (b >= NB) return;
    int len = TSTEPS + 1;
    for (int t = TSTEPS - 1; t >= 0; t--)
        if (resps[b * TSTEPS + t] == 2) len = t + 1;
    lens[b] = len;
}

extern "C" void kernel_launch(void* const* d_in, const int* in_sizes, int n_in,
                              void* d_out, int out_size, void* d_ws, size_t ws_size,
                              hipStream_t stream) {
    const float* zs   = (const float*)d_in[0];
    const float* cs   = (const float*)d_in[1];
    const float* emb  = (const float*)d_in[2];
    const float* Wih  = (const float*)d_in[3];
    const float* Whh  = (const float*)d_in[4];
    const float* bih  = (const float*)d_in[5];
    const float* bhh  = (const float*)d_in[6];
    const float* Wout = (const float*)d_in[7];
    const float* bout = (const float*)d_in[8];
    int* out = (int*)d_out;  // [64*32 resps][64 lens], int32

    char* ws = (char*)d_ws;
    float4* ht4  = (float4*)ws; ws += (size_t)256 * NB * 16;          // 256 KB
    float*  gpart = (float*)ws; ws += (size_t)4 * NB * NC6 * 4;       // 6.3 MB
    short*  Hsp  = (short*)ws;  ws += (size_t)NB * 2048 * 2;          // 256 KB
    short*  Xsp  = (short*)ws;  ws += (size_t)NB * 2048 * 2;          // 256 KB
    float*  wnorm = (float*)ws; ws += (size_t)NV * 4;                 // 128 KB
    float*  hnorm = (float*)ws; ws += 256;
    float*  bmlow = (float*)ws; ws += (size_t)NB * BML * 4;           // 128 KB
    unsigned long long* best = (unsigned long long*)ws; ws += NB * 8;
    float*  lb   = (float*)ws;  ws += (size_t)NB * NV * 4;            // 8.2 MB
    short*  Wbf  = (short*)ws;  ws += (size_t)NV * HD * 2;            // 65.5 MB
    short*  WihSp = (short*)ws; ws += (size_t)H3 * 2048 * 2;          // 12.6 MB
    short*  WhhSp = (short*)ws; ws += (size_t)H3 * 2048 * 2;          // 12.6 MB

    wsplit2_kernel<<<NC6, 256, 0, stream>>>(Wih, Whh, WihSp, WhhSp);
    wbf_kernel<<<NV, 256, 0, stream>>>(Wout, Wbf, wnorm);
    init_kernel<<<NB, 256, 0, stream>>>(zs, cs, emb, ht4, Hsp, Xsp, hnorm, best);
    for (int t = 0; t < TSTEPS; t++) {
        gates_mfma<<<96 * 4, 256, 0, stream>>>(Xsp, Hsp, WihSp, WhhSp, gpart);
        gru_fuse<<<NB, 256, 0, stream>>>(gpart, bih, bhh, ht4, Hsp, hnorm, best);
        logits_lb<<<LBLK, 256, 0, stream>>>(Hsp, Wbf, bout, wnorm, hnorm, lb, bmlow);
        select2_kernel<<<NB * NSLICE, 256, 0, stream>>>(lb, wnorm, hnorm, bmlow,
                                                        Wout, bout, ht4, best);
        gather_kernel<<<NB, 256, 0, stream>>>(best, emb, out, t, Xsp);
    }
    resp_lens_kernel<<<1, 64, 0, stream>>>(out, out + NB * TSTEPS);
}